// Round 1
// baseline (109.743 us; speedup 1.0000x reference)
//
#include <hip/hip_runtime.h>

// FsCoding10 fast-forward: per element,
//   v = |x|; z = 0; out = 0
//   for t in 0..15: v -= z*h[t]; z = ((v - T[t])/(|v|+1) > 0); out += z*d[t]
//   return out * sign(x)
// Since |v|+1 > 0 always and fp32 subtraction never rounds across zero,
// z == (v > T[t]) exactly -> no division needed.
// z*h and z*d are exact (z in {0,1}), so fmaf matches numpy bitwise.

#define NTHREADS 256
#define NBLOCKS  8192

__device__ __forceinline__ float fs10_one(float xi) {
    // Constants from the reference source (_SIGMOID_H/D/T), fp32.
    constexpr float H[16] = {
        -0.11408895f, 1.1758447f, 1.0135335f, 1.2213913f,
         1.3241712f,  0.8555309f, 1.4268297f, 1.1778928f,
         0.80728793f, 0.43790972f, 0.2571573f, 0.13942857f,
        -0.3750314f,  0.08095932f, 1.354895f,  5.0583024f};
    constexpr float D[16] = {
         1.1759424f,  1.0134453f, 1.221452f,  1.3243698f,
         0.85503244f, 1.4270093f, 1.1782365f, 0.8076809f,
         0.43830687f, 0.2571347f, 0.13936771f, -0.04276754f,
         0.07785574f, 0.05046117f, 0.10240205f, 0.02330057f};
    constexpr float T[16] = {
         1.3393638f,  1.3052133f, 1.3697962f, 1.3982388f,
         1.264561f,   1.3956275f, 1.1693456f, 0.79711413f,
         0.42847168f, 0.24717589f, 0.13019533f, 0.52669114f,
         0.06617433f, 0.0366448f, 1.0000271f, 0.01022558f};

    float v   = fabsf(xi);
    float z   = 0.0f;
    float acc = 0.0f;
#pragma unroll
    for (int t = 0; t < 16; ++t) {
        v   = fmaf(-z, H[t], v);        // v -= z*h[t]  (exact: z in {0,1})
        z   = (v > T[t]) ? 1.0f : 0.0f; // spike((v-T)/(|v|+1)) == (v > T)
        acc = fmaf(z, D[t], acc);       // out += z*d[t]
    }
    return copysignf(acc, xi);          // out * sign(x); acc==0 when x==0
}

__global__ __launch_bounds__(NTHREADS)
void fs10_kernel(const float4* __restrict__ x, float4* __restrict__ out,
                 int n4, const float* __restrict__ xs, float* __restrict__ outs,
                 int n) {
    const int stride = gridDim.x * blockDim.x;
    const int tid0   = blockIdx.x * blockDim.x + threadIdx.x;
    for (int i = tid0; i < n4; i += stride) {
        float4 xv = x[i];
        float4 r;
        r.x = fs10_one(xv.x);
        r.y = fs10_one(xv.y);
        r.z = fs10_one(xv.z);
        r.w = fs10_one(xv.w);
        out[i] = r;
    }
    // Scalar tail (n % 4 != 0) — not hit for this problem size, kept for safety.
    const int tail_base = n4 << 2;
    for (int i = tail_base + tid0; i < n; i += stride) {
        outs[i] = fs10_one(xs[i]);
    }
}

extern "C" void kernel_launch(void* const* d_in, const int* in_sizes, int n_in,
                              void* d_out, int out_size, void* d_ws, size_t ws_size,
                              hipStream_t stream) {
    const float* x = (const float*)d_in[0];
    float* out     = (float*)d_out;
    const int n    = in_sizes[0];
    const int n4   = n >> 2;

    int blocks = (n4 + NTHREADS - 1) / NTHREADS;
    if (blocks > NBLOCKS) blocks = NBLOCKS;
    if (blocks < 1) blocks = 1;

    fs10_kernel<<<blocks, NTHREADS, 0, stream>>>(
        (const float4*)x, (float4*)out, n4, x, out, n);
}